// Round 1
// baseline (196.667 us; speedup 1.0000x reference)
//
#include <hip/hip_runtime.h>

#define L   2048
#define NM  10
#define NG  20
#define NF  30

#define OFF_T   0
#define OFF_SP  2048
#define OFF_LC  4096
#define OFF_LS  (4096 + NM*L)
#define FWS_FLOATS (OFF_LS + NM*L)   // 45056 floats = 180224 bytes (8-aligned)

// ws layout: [float fws[45056]] [double sum_t, sum_tt] [double mse_c[80000]]
//            [double mse_f[27000]] [int coarse_idx, fine_idx]

__device__ __forceinline__ float grid20(int i) {
  // jnp.logspace(-1,1,20)[i] = 10^(-1 + 2i/19)
  double e = -1.0 + 2.0 * (double)i / 19.0;
  return (float)exp2(e * 3.3219280948873623478703194294894);
}

__device__ __forceinline__ float finev(float c, int j) {
  // jnp.linspace(0.8c, 1.2c, 30)[j]
  return (float)((double)c * 0.8 + (double)j * ((double)c * 0.4 / 29.0));
}

// ---------------- setup: normalize target, compute sum_t / sum_tt ----------
__global__ __launch_bounds__(256) void k_setup(const float* __restrict__ x,
                                               float* __restrict__ fws,
                                               double* __restrict__ dws) {
  int tid = threadIdx.x;
  int lane = tid & 63, w = tid >> 6;
  __shared__ double sh[8];
  __shared__ double s_mean, s_d;

  double sx = 0.0, sxx = 0.0;
  for (int l = tid; l < L; l += 256) {
    double v = (double)x[l];
    sx += v; sxx += v * v;
  }
  for (int o = 32; o > 0; o >>= 1) { sx += __shfl_down(sx, o); sxx += __shfl_down(sxx, o); }
  if (lane == 0) { sh[w] = sx; sh[4 + w] = sxx; }
  __syncthreads();
  if (tid == 0) {
    sx = sh[0] + sh[1] + sh[2] + sh[3];
    sxx = sh[4] + sh[5] + sh[6] + sh[7];
    double mean = sx / (double)L;
    double S = sxx - sx * sx / (double)L; if (S < 0.0) S = 0.0;
    double sd = sqrt(S / (double)(L - 1));
    s_mean = mean; s_d = sd + 1e-6;
  }
  __syncthreads();
  double mean = s_mean, d = s_d;

  double st = 0.0, stt = 0.0;
  for (int l = tid; l < L; l += 256) {
    float tv = (float)(((double)x[l] - mean) / d);
    fws[OFF_T + l] = tv;
    st += (double)tv; stt += (double)tv * (double)tv;
  }
  for (int o = 32; o > 0; o >>= 1) { st += __shfl_down(st, o); stt += __shfl_down(stt, o); }
  __syncthreads();
  if (lane == 0) { sh[w] = st; sh[4 + w] = stt; }
  __syncthreads();
  if (tid == 0) {
    dws[0] = sh[0] + sh[1] + sh[2] + sh[3];
    dws[1] = sh[4] + sh[5] + sh[6] + sh[7];
  }
}

// ---------------- tables: sin(phi), log2|cos(m phi/4)|, log2|sin(m phi/4)| --
__global__ __launch_bounds__(256) void k_tables(const int* __restrict__ freqp,
                                                float* __restrict__ fws) {
  int idx = blockIdx.x * 256 + threadIdx.x;      // [0, NM*L)
  if (idx >= NM * L) return;
  int m = idx / L, l = idx % L;
  double freq = (double)freqp[0];
  double t = -1.0 + 2.0 * (double)l / 2047.0;
  double phi = 6.2831853071795864769 * freq * t;
  if (m == 0) fws[OFF_SP + l] = (float)sin(phi);
  double ang = (double)(m + 1) * phi * 0.25;
  double sv, cv;
  sincos(ang, &sv, &cv);
  fws[OFF_LC + m * L + l] = (float)log2(fabs(cv));
  fws[OFF_LS + m * L + l] = (float)log2(fabs(sv));
}

// ---------------- coarse scan: one wave per (m, i2, i3), loop i1 -----------
__global__ __launch_bounds__(256) void k_coarse(const float* __restrict__ fws,
                                                const double* __restrict__ dws,
                                                double* __restrict__ mse_c) {
  int gwid = (blockIdx.x * 256 + threadIdx.x) >> 6;   // [0, 4000)
  int lane = threadIdx.x & 63;
  if (gwid >= NM * NG * NG) return;
  int m  = gwid / (NG * NG);
  int i2 = (gwid / NG) % NG;
  int i3 = gwid % NG;

  const float* lc = fws + OFF_LC + m * L;
  const float* ls = fws + OFF_LS + m * L;
  const float* sp = fws + OFF_SP;
  const float* tt = fws + OFF_T;
  float n2 = grid20(i2), n3 = grid20(i3);

  float lsum[32], spv[32], ttv[32];
#pragma unroll
  for (int k = 0; k < 32; k++) {
    int l = lane + (k << 6);
    float a2 = exp2f(n2 * lc[l]);
    float a3 = exp2f(n3 * ls[l]);
    lsum[k] = log2f(a2 + a3);
    spv[k] = sp[l];
    ttv[k] = tt[l];
  }
  double sum_t = dws[0], sum_tt = dws[1];

  for (int i1 = 0; i1 < NG; i1++) {
    float r = -1.0f / grid20(i1);
    double sg = 0.0, sgg = 0.0, sgt = 0.0;
#pragma unroll
    for (int k = 0; k < 32; k++) {
      float g = exp2f(r * lsum[k]) * spv[k];
      double gd = (double)g;
      sg += gd; sgg += gd * gd; sgt += gd * (double)ttv[k];
    }
    for (int o = 32; o > 0; o >>= 1) {
      sg  += __shfl_down(sg, o);
      sgg += __shfl_down(sgg, o);
      sgt += __shfl_down(sgt, o);
    }
    if (lane == 0) {
      double mean = sg / (double)L;
      double S = sgg - sg * sg / (double)L; if (S < 0.0) S = 0.0;
      double sd = sqrt(S / (double)(L - 1));
      double d = sd + 1e-6;
      double mse = (S / (d * d) - 2.0 * (sgt - mean * sum_t) / d + sum_tt) / (double)L;
      int idx = ((m * NG + i1) * NG + i2) * NG + i3;
      mse_c[idx] = mse;
    }
  }
}

// ---------------- fine scan: one wave per (j2, j3), loop j1 ----------------
__global__ __launch_bounds__(256) void k_fine(const float* __restrict__ fws,
                                              const double* __restrict__ dws,
                                              const int* __restrict__ cidx,
                                              double* __restrict__ mse_f) {
  int gwid = (blockIdx.x * 256 + threadIdx.x) >> 6;   // [0, 900)
  int lane = threadIdx.x & 63;
  if (gwid >= NF * NF) return;

  int ci = *cidx;
  int m  = ci / (NG * NG * NG);
  int rr = ci % (NG * NG * NG);
  int i1 = rr / (NG * NG), i2 = (rr / NG) % NG, i3 = rr % NG;
  float cn1 = grid20(i1), cn2 = grid20(i2), cn3 = grid20(i3);

  int j2 = gwid / NF, j3 = gwid % NF;
  float n2 = finev(cn2, j2), n3 = finev(cn3, j3);

  const float* lc = fws + OFF_LC + m * L;
  const float* ls = fws + OFF_LS + m * L;
  const float* sp = fws + OFF_SP;
  const float* tt = fws + OFF_T;

  float lsum[32], spv[32], ttv[32];
#pragma unroll
  for (int k = 0; k < 32; k++) {
    int l = lane + (k << 6);
    float a2 = exp2f(n2 * lc[l]);
    float a3 = exp2f(n3 * ls[l]);
    lsum[k] = log2f(a2 + a3);
    spv[k] = sp[l];
    ttv[k] = tt[l];
  }
  double sum_t = dws[0], sum_tt = dws[1];

  for (int j1 = 0; j1 < NF; j1++) {
    float r = -1.0f / finev(cn1, j1);
    double sg = 0.0, sgg = 0.0, sgt = 0.0;
#pragma unroll
    for (int k = 0; k < 32; k++) {
      float g = exp2f(r * lsum[k]) * spv[k];
      double gd = (double)g;
      sg += gd; sgg += gd * gd; sgt += gd * (double)ttv[k];
    }
    for (int o = 32; o > 0; o >>= 1) {
      sg  += __shfl_down(sg, o);
      sgg += __shfl_down(sgg, o);
      sgt += __shfl_down(sgt, o);
    }
    if (lane == 0) {
      double mean = sg / (double)L;
      double S = sgg - sg * sg / (double)L; if (S < 0.0) S = 0.0;
      double sd = sqrt(S / (double)(L - 1));
      double d = sd + 1e-6;
      double mse = (S / (d * d) - 2.0 * (sgt - mean * sum_t) / d + sum_tt) / (double)L;
      int idx = (j1 * NF + j2) * NF + j3;
      mse_f[idx] = mse;
    }
  }
}

// ---------------- argmin with first-index tie break ------------------------
__global__ void k_argmin(const double* __restrict__ v, int n, int* __restrict__ outIdx) {
  double best = 1e300; int bi = n;
  for (int i = threadIdx.x; i < n; i += blockDim.x) {
    double x = v[i];
    if (x < best) { best = x; bi = i; }
  }
  for (int o = 32; o > 0; o >>= 1) {
    double ob = __shfl_down(best, o);
    int oi = __shfl_down(bi, o);
    if (ob < best || (ob == best && oi < bi)) { best = ob; bi = oi; }
  }
  __shared__ double sb[16];
  __shared__ int si[16];
  int lane = threadIdx.x & 63, w = threadIdx.x >> 6;
  if (lane == 0) { sb[w] = best; si[w] = bi; }
  __syncthreads();
  if (threadIdx.x == 0) {
    int nw = blockDim.x >> 6;
    for (int k = 1; k < nw; k++) {
      if (sb[k] < best || (sb[k] == best && si[k] < bi)) { best = sb[k]; bi = si[k]; }
    }
    *outIdx = bi;
  }
}

// ---------------- emit the 4 outputs ---------------------------------------
__global__ void k_out(const int* __restrict__ cidx, const int* __restrict__ fidx,
                      float* __restrict__ out) {
  if (threadIdx.x == 0) {
    int ci = *cidx;
    int m  = ci / (NG * NG * NG);
    int rr = ci % (NG * NG * NG);
    int i1 = rr / (NG * NG), i2 = (rr / NG) % NG, i3 = rr % NG;
    int fi = *fidx;
    int f1 = fi / (NF * NF), f2 = (fi / NF) % NF, f3 = fi % NF;
    out[0] = (float)(m + 1);
    out[1] = finev(grid20(i1), f1);
    out[2] = finev(grid20(i2), f2);
    out[3] = finev(grid20(i3), f3);
  }
}

extern "C" void kernel_launch(void* const* d_in, const int* in_sizes, int n_in,
                              void* d_out, int out_size, void* d_ws, size_t ws_size,
                              hipStream_t stream) {
  const float* x = (const float*)d_in[0];
  const int* freqp = (const int*)d_in[1];
  float* out = (float*)d_out;

  float* fws = (float*)d_ws;
  double* dws = (double*)((char*)d_ws + FWS_FLOATS * sizeof(float));
  double* mse_c = dws + 2;                 // 80000
  double* mse_f = mse_c + NM * NG * NG * NG; // 27000
  int* ires = (int*)(mse_f + NF * NF * NF);  // [0]=coarse idx, [1]=fine idx

  hipLaunchKernelGGL(k_setup,  dim3(1),    dim3(256), 0, stream, x, fws, dws);
  hipLaunchKernelGGL(k_tables, dim3((NM * L + 255) / 256), dim3(256), 0, stream, freqp, fws);
  hipLaunchKernelGGL(k_coarse, dim3(1000), dim3(256), 0, stream, fws, dws, mse_c);
  hipLaunchKernelGGL(k_argmin, dim3(1),    dim3(1024), 0, stream, mse_c, NM * NG * NG * NG, ires + 0);
  hipLaunchKernelGGL(k_fine,   dim3(225),  dim3(256), 0, stream, fws, dws, ires + 0, mse_f);
  hipLaunchKernelGGL(k_argmin, dim3(1),    dim3(1024), 0, stream, mse_f, NF * NF * NF, ires + 1);
  hipLaunchKernelGGL(k_out,    dim3(1),    dim3(64),  0, stream, ires + 0, ires + 1, out);
}

// Round 2
// 144.904 us; speedup vs baseline: 1.3572x; 1.3572x over previous
//
#include <hip/hip_runtime.h>

#define L   2048
#define NM  10
#define NG  20
#define NF  30

#define NCH_C 2     // coarse: 2 chunks of 10 i1 values
#define CH_C  10
#define NCH_F 5     // fine: 5 chunks of 6 j1 values
#define CH_F  6

#define OFF_T   0
#define OFF_SP  2048
#define OFF_LC  4096
#define OFF_LS  (4096 + NM*L)
#define FWS_FLOATS (OFF_LS + NM*L)   // 45056 floats (16B-aligned sections)

#define NB_C 125    // argmin stage-1 blocks (coarse)
#define NB_F 54     // argmin stage-1 blocks (fine)

__device__ __forceinline__ float grid20(int i) {
  // jnp.logspace(-1,1,20)[i] = 10^(-1 + 2i/19)
  double e = -1.0 + 2.0 * (double)i / 19.0;
  return (float)exp2(e * 3.3219280948873623478703194294894);
}

__device__ __forceinline__ float finev(float c, int j) {
  // jnp.linspace(0.8c, 1.2c, 30)[j]
  return (float)((double)c * 0.8 + (double)j * ((double)c * 0.4 / 29.0));
}

// ---------------- setup: normalize target, compute sum_t / sum_tt ----------
__global__ __launch_bounds__(256) void k_setup(const float* __restrict__ x,
                                               float* __restrict__ fws,
                                               double* __restrict__ dws) {
  int tid = threadIdx.x;
  int lane = tid & 63, w = tid >> 6;
  __shared__ double sh[8];
  __shared__ double s_mean, s_d;

  double sx = 0.0, sxx = 0.0;
  for (int l = tid; l < L; l += 256) {
    double v = (double)x[l];
    sx += v; sxx += v * v;
  }
  for (int o = 32; o > 0; o >>= 1) { sx += __shfl_down(sx, o); sxx += __shfl_down(sxx, o); }
  if (lane == 0) { sh[w] = sx; sh[4 + w] = sxx; }
  __syncthreads();
  if (tid == 0) {
    sx = sh[0] + sh[1] + sh[2] + sh[3];
    sxx = sh[4] + sh[5] + sh[6] + sh[7];
    double mean = sx / (double)L;
    double S = sxx - sx * sx / (double)L; if (S < 0.0) S = 0.0;
    double sd = sqrt(S / (double)(L - 1));
    s_mean = mean; s_d = sd + 1e-6;
  }
  __syncthreads();
  double mean = s_mean, d = s_d;

  double st = 0.0, stt = 0.0;
  for (int l = tid; l < L; l += 256) {
    float tv = (float)(((double)x[l] - mean) / d);
    fws[OFF_T + l] = tv;
    st += (double)tv; stt += (double)tv * (double)tv;
  }
  for (int o = 32; o > 0; o >>= 1) { st += __shfl_down(st, o); stt += __shfl_down(stt, o); }
  __syncthreads();
  if (lane == 0) { sh[w] = st; sh[4 + w] = stt; }
  __syncthreads();
  if (tid == 0) {
    dws[0] = sh[0] + sh[1] + sh[2] + sh[3];
    dws[1] = sh[4] + sh[5] + sh[6] + sh[7];
  }
}

// ---------------- tables: sin(phi), log2|cos(m phi/4)|, log2|sin(m phi/4)| --
__global__ __launch_bounds__(256) void k_tables(const int* __restrict__ freqp,
                                                float* __restrict__ fws) {
  int idx = blockIdx.x * 256 + threadIdx.x;      // [0, NM*L)
  if (idx >= NM * L) return;
  int m = idx / L, l = idx % L;
  double freq = (double)freqp[0];
  double t = -1.0 + 2.0 * (double)l / 2047.0;
  double phi = 6.2831853071795864769 * freq * t;
  if (m == 0) fws[OFF_SP + l] = (float)sin(phi);
  double ang = (double)(m + 1) * phi * 0.25;
  double sv, cv;
  sincos(ang, &sv, &cv);
  fws[OFF_LC + m * L + l] = (float)log2(fabs(cv));
  fws[OFF_LS + m * L + l] = (float)log2(fabs(sv));
}

// ---------------- shared scan body (f32 accumulate, f64 finalize) ----------
__device__ __forceinline__ void scan_setup(const float* __restrict__ lc,
                                           const float* __restrict__ ls,
                                           const float* __restrict__ sp,
                                           const float* __restrict__ tt,
                                           int lane, float n2, float n3,
                                           float* lsum, float* spv, float* ttv) {
#pragma unroll
  for (int k = 0; k < 8; k++) {
    int base = lane * 4 + k * 256;
    float4 c4 = *reinterpret_cast<const float4*>(lc + base);
    float4 s4 = *reinterpret_cast<const float4*>(ls + base);
    float4 p4 = *reinterpret_cast<const float4*>(sp + base);
    float4 t4 = *reinterpret_cast<const float4*>(tt + base);
    lsum[k*4+0] = log2f(exp2f(n2 * c4.x) + exp2f(n3 * s4.x));
    lsum[k*4+1] = log2f(exp2f(n2 * c4.y) + exp2f(n3 * s4.y));
    lsum[k*4+2] = log2f(exp2f(n2 * c4.z) + exp2f(n3 * s4.z));
    lsum[k*4+3] = log2f(exp2f(n2 * c4.w) + exp2f(n3 * s4.w));
    spv[k*4+0] = p4.x; spv[k*4+1] = p4.y; spv[k*4+2] = p4.z; spv[k*4+3] = p4.w;
    ttv[k*4+0] = t4.x; ttv[k*4+1] = t4.y; ttv[k*4+2] = t4.z; ttv[k*4+3] = t4.w;
  }
}

__device__ __forceinline__ void scan_one(float r, const float* lsum,
                                         const float* spv, const float* ttv,
                                         int lane, double sum_t, double sum_tt,
                                         double* __restrict__ mse_out) {
  float sg = 0.0f, sgg = 0.0f, sgt = 0.0f;
#pragma unroll
  for (int k = 0; k < 32; k++) {
    float e = exp2f(r * lsum[k]);
    float g = e * spv[k];
    sg += g; sgg += g * g; sgt += g * ttv[k];
  }
  for (int o = 32; o > 0; o >>= 1) {
    sg  += __shfl_down(sg, o);
    sgg += __shfl_down(sgg, o);
    sgt += __shfl_down(sgt, o);
  }
  if (lane == 0) {
    double sgd = (double)sg, sggd = (double)sgg, sgtd = (double)sgt;
    double mean = sgd / (double)L;
    double S = sggd - sgd * sgd / (double)L; if (S < 0.0) S = 0.0;
    double sd = sqrt(S / (double)(L - 1));
    double d = sd + 1e-6;
    double mse = (S / (d * d) - 2.0 * (sgtd - mean * sum_t) / d + sum_tt) / (double)L;
    *mse_out = mse;
  }
}

// ---------------- coarse scan: one wave per (m,i2,i3,chunk), 10 i1 each ----
__global__ __launch_bounds__(256) void k_coarse(const float* __restrict__ fws,
                                                const double* __restrict__ dws,
                                                double* __restrict__ mse_c) {
  int gwid = (blockIdx.x * 256 + threadIdx.x) >> 6;   // [0, 8000)
  int lane = threadIdx.x & 63;
  if (gwid >= NM * NG * NG * NCH_C) return;
  int combo = gwid >> 1;           // NCH_C == 2
  int ch = gwid & 1;
  int m  = combo / (NG * NG);
  int i2 = (combo / NG) % NG;
  int i3 = combo % NG;

  const float* lc = fws + OFF_LC + m * L;
  const float* ls = fws + OFF_LS + m * L;
  const float* sp = fws + OFF_SP;
  const float* tt = fws + OFF_T;
  float n2 = grid20(i2), n3 = grid20(i3);

  float lsum[32], spv[32], ttv[32];
  scan_setup(lc, ls, sp, tt, lane, n2, n3, lsum, spv, ttv);
  double sum_t = dws[0], sum_tt = dws[1];

  int i10 = ch * CH_C;
  for (int i1 = i10; i1 < i10 + CH_C; i1++) {
    float r = -1.0f / grid20(i1);
    int idx = ((m * NG + i1) * NG + i2) * NG + i3;
    scan_one(r, lsum, spv, ttv, lane, sum_t, sum_tt, mse_c + idx);
  }
}

// ---------------- fine scan: one wave per (j2,j3,chunk), 6 j1 each ---------
__global__ __launch_bounds__(256) void k_fine(const float* __restrict__ fws,
                                              const double* __restrict__ dws,
                                              const int* __restrict__ cidx,
                                              double* __restrict__ mse_f) {
  int gwid = (blockIdx.x * 256 + threadIdx.x) >> 6;   // [0, 4500)
  int lane = threadIdx.x & 63;
  if (gwid >= NF * NF * NCH_F) return;
  int combo = gwid / NCH_F;
  int ch = gwid % NCH_F;

  int ci = *cidx;
  int m  = ci / (NG * NG * NG);
  int rr = ci % (NG * NG * NG);
  int i1 = rr / (NG * NG), i2 = (rr / NG) % NG, i3 = rr % NG;
  float cn1 = grid20(i1), cn2 = grid20(i2), cn3 = grid20(i3);

  int j2 = combo / NF, j3 = combo % NF;
  float n2 = finev(cn2, j2), n3 = finev(cn3, j3);

  const float* lc = fws + OFF_LC + m * L;
  const float* ls = fws + OFF_LS + m * L;
  const float* sp = fws + OFF_SP;
  const float* tt = fws + OFF_T;

  float lsum[32], spv[32], ttv[32];
  scan_setup(lc, ls, sp, tt, lane, n2, n3, lsum, spv, ttv);
  double sum_t = dws[0], sum_tt = dws[1];

  int j10 = ch * CH_F;
  for (int j1 = j10; j1 < j10 + CH_F; j1++) {
    float r = -1.0f / finev(cn1, j1);
    int idx = (j1 * NF + j2) * NF + j3;
    scan_one(r, lsum, spv, ttv, lane, sum_t, sum_tt, mse_f + idx);
  }
}

// ---------------- two-stage argmin, first-index tie break ------------------
__global__ __launch_bounds__(256) void k_argmin1(const double* __restrict__ v, int n,
                                                 int per_block,
                                                 double* __restrict__ pv,
                                                 int* __restrict__ pi) {
  int b = blockIdx.x;
  int lo = b * per_block;
  int hi = lo + per_block; if (hi > n) hi = n;
  double best = 1e300; int bi = n;
  for (int i = lo + threadIdx.x; i < hi; i += 256) {
    double x = v[i];
    if (x < best || (x == best && i < bi)) { best = x; bi = i; }
  }
  int lane = threadIdx.x & 63, w = threadIdx.x >> 6;
  for (int o = 32; o > 0; o >>= 1) {
    double ob = __shfl_down(best, o);
    int oi = __shfl_down(bi, o);
    if (ob < best || (ob == best && oi < bi)) { best = ob; bi = oi; }
  }
  __shared__ double sb[4];
  __shared__ int si[4];
  if (lane == 0) { sb[w] = best; si[w] = bi; }
  __syncthreads();
  if (threadIdx.x == 0) {
    for (int k = 1; k < 4; k++) {
      if (sb[k] < best || (sb[k] == best && si[k] < bi)) { best = sb[k]; bi = si[k]; }
    }
    pv[b] = best; pi[b] = bi;
  }
}

__global__ __launch_bounds__(256) void k_argmin2(const double* __restrict__ pv,
                                                 const int* __restrict__ pi, int nb,
                                                 int* __restrict__ outIdx) {
  double best = 1e300; int bi = 0x7fffffff;
  for (int i = threadIdx.x; i < nb; i += 256) {
    double x = pv[i]; int ix = pi[i];
    if (x < best || (x == best && ix < bi)) { best = x; bi = ix; }
  }
  int lane = threadIdx.x & 63, w = threadIdx.x >> 6;
  for (int o = 32; o > 0; o >>= 1) {
    double ob = __shfl_down(best, o);
    int oi = __shfl_down(bi, o);
    if (ob < best || (ob == best && oi < bi)) { best = ob; bi = oi; }
  }
  __shared__ double sb[4];
  __shared__ int si[4];
  if (lane == 0) { sb[w] = best; si[w] = bi; }
  __syncthreads();
  if (threadIdx.x == 0) {
    for (int k = 1; k < 4; k++) {
      if (sb[k] < best || (sb[k] == best && si[k] < bi)) { best = sb[k]; bi = si[k]; }
    }
    *outIdx = bi;
  }
}

// ---------------- emit the 4 outputs ---------------------------------------
__global__ void k_out(const int* __restrict__ cidx, const int* __restrict__ fidx,
                      float* __restrict__ out) {
  if (threadIdx.x == 0) {
    int ci = *cidx;
    int m  = ci / (NG * NG * NG);
    int rr = ci % (NG * NG * NG);
    int i1 = rr / (NG * NG), i2 = (rr / NG) % NG, i3 = rr % NG;
    int fi = *fidx;
    int f1 = fi / (NF * NF), f2 = (fi / NF) % NF, f3 = fi % NF;
    out[0] = (float)(m + 1);
    out[1] = finev(grid20(i1), f1);
    out[2] = finev(grid20(i2), f2);
    out[3] = finev(grid20(i3), f3);
  }
}

extern "C" void kernel_launch(void* const* d_in, const int* in_sizes, int n_in,
                              void* d_out, int out_size, void* d_ws, size_t ws_size,
                              hipStream_t stream) {
  const float* x = (const float*)d_in[0];
  const int* freqp = (const int*)d_in[1];
  float* out = (float*)d_out;

  float* fws = (float*)d_ws;
  double* dws = (double*)((char*)d_ws + FWS_FLOATS * sizeof(float));
  double* mse_c = dws + 2;                     // 80000
  double* mse_f = mse_c + NM * NG * NG * NG;   // 27000
  double* pv    = mse_f + NF * NF * NF;        // max(NB_C, NB_F) = 125
  int*    pi    = (int*)(pv + NB_C);           // 125
  int*    ires  = pi + NB_C;                   // [0]=coarse idx, [1]=fine idx

  const int n_c = NM * NG * NG * NG;           // 80000
  const int n_f = NF * NF * NF;                // 27000

  hipLaunchKernelGGL(k_setup,  dim3(1),    dim3(256), 0, stream, x, fws, dws);
  hipLaunchKernelGGL(k_tables, dim3((NM * L + 255) / 256), dim3(256), 0, stream, freqp, fws);
  hipLaunchKernelGGL(k_coarse, dim3((NM * NG * NG * NCH_C) / 4), dim3(256), 0, stream, fws, dws, mse_c);
  hipLaunchKernelGGL(k_argmin1, dim3(NB_C), dim3(256), 0, stream, mse_c, n_c, (n_c + NB_C - 1) / NB_C, pv, pi);
  hipLaunchKernelGGL(k_argmin2, dim3(1),    dim3(256), 0, stream, pv, pi, NB_C, ires + 0);
  hipLaunchKernelGGL(k_fine,   dim3((NF * NF * NCH_F + 3) / 4), dim3(256), 0, stream, fws, dws, ires + 0, mse_f);
  hipLaunchKernelGGL(k_argmin1, dim3(NB_F), dim3(256), 0, stream, mse_f, n_f, (n_f + NB_F - 1) / NB_F, pv, pi);
  hipLaunchKernelGGL(k_argmin2, dim3(1),    dim3(256), 0, stream, pv, pi, NB_F, ires + 1);
  hipLaunchKernelGGL(k_out,    dim3(1),    dim3(64),  0, stream, ires + 0, ires + 1, out);
}

// Round 3
// 112.892 us; speedup vs baseline: 1.7421x; 1.2836x over previous
//
#include <hip/hip_runtime.h>

#define L   2048
#define NM  10
#define NG  20
#define NF  30

// fws layout (floats): tt[L], then float4 tab[NM*L] = {log2|cos|, log2|sin|, sin(phi), 0}
#define OFF_T   0
#define OFF_TAB 2048
#define FWS_FLOATS (OFF_TAB + 4*NM*L)   // 2048 + 81920 = 83968 floats

#define NBC 313   // ceil(80000/256)
#define NBF 106   // ceil(27000/256)

__device__ __forceinline__ float grid20(int i) {
  // jnp.logspace(-1,1,20)[i] = 10^(-1 + 2i/19)
  double e = -1.0 + 2.0 * (double)i / 19.0;
  return (float)exp2(e * 3.3219280948873623478703194294894);
}

__device__ __forceinline__ float finev(float c, int j) {
  // jnp.linspace(0.8c, 1.2c, 30)[j]
  return (float)((double)c * 0.8 + (double)j * ((double)c * 0.4 / 29.0));
}

// ---------------- K1: setup (block 0) + tables (blocks 1..80) --------------
__global__ __launch_bounds__(256) void k_init(const float* __restrict__ x,
                                              const int* __restrict__ freqp,
                                              float* __restrict__ fws,
                                              double* __restrict__ dws) {
  if (blockIdx.x == 0) {
    int tid = threadIdx.x;
    int lane = tid & 63, w = tid >> 6;
    __shared__ double sh[8];
    __shared__ double s_mean, s_d;

    double sx = 0.0, sxx = 0.0;
    for (int l = tid; l < L; l += 256) {
      double v = (double)x[l];
      sx += v; sxx += v * v;
    }
    for (int o = 32; o > 0; o >>= 1) { sx += __shfl_down(sx, o); sxx += __shfl_down(sxx, o); }
    if (lane == 0) { sh[w] = sx; sh[4 + w] = sxx; }
    __syncthreads();
    if (tid == 0) {
      sx = sh[0] + sh[1] + sh[2] + sh[3];
      sxx = sh[4] + sh[5] + sh[6] + sh[7];
      double mean = sx / (double)L;
      double S = sxx - sx * sx / (double)L; if (S < 0.0) S = 0.0;
      double sd = sqrt(S / (double)(L - 1));
      s_mean = mean; s_d = sd + 1e-6;
    }
    __syncthreads();
    double mean = s_mean, d = s_d;

    double st = 0.0, stt = 0.0;
    for (int l = tid; l < L; l += 256) {
      float tv = (float)(((double)x[l] - mean) / d);
      fws[OFF_T + l] = tv;
      st += (double)tv; stt += (double)tv * (double)tv;
    }
    for (int o = 32; o > 0; o >>= 1) { st += __shfl_down(st, o); stt += __shfl_down(stt, o); }
    __syncthreads();
    if (lane == 0) { sh[w] = st; sh[4 + w] = stt; }
    __syncthreads();
    if (tid == 0) {
      dws[0] = sh[0] + sh[1] + sh[2] + sh[3];
      dws[1] = sh[4] + sh[5] + sh[6] + sh[7];
    }
  } else {
    int idx = (blockIdx.x - 1) * 256 + threadIdx.x;   // [0, NM*L)
    if (idx < NM * L) {
      int m = idx / L, l = idx % L;
      double freq = (double)freqp[0];
      double t = -1.0 + 2.0 * (double)l / 2047.0;
      double phi = 6.2831853071795864769 * freq * t;
      double ang = (double)(m + 1) * phi * 0.25;
      double sv, cv;
      sincos(ang, &sv, &cv);
      float4 v;
      v.x = (float)log2(fabs(cv));
      v.y = (float)log2(fabs(sv));
      v.z = (float)sin(phi);
      v.w = 0.0f;
      reinterpret_cast<float4*>(fws + OFF_TAB)[m * L + l] = v;
    }
  }
}

// ---------------- K2: coarse partial sums ----------------------------------
// wave = (combo, chunk); combo=(m,i2,i3) in [0,4000); chunk in {0,1} (1024 elems)
// per lane: 20 i1 x {sg,sgg,sgt} f32 accumulators in registers
__global__ __launch_bounds__(256) void k_coarse(const float* __restrict__ fws,
                                                float* __restrict__ part) {
  int gwid = (blockIdx.x * 256 + threadIdx.x) >> 6;   // [0, 8000)
  int lane = threadIdx.x & 63;
  int combo = gwid >> 1, ch = gwid & 1;
  int m = combo / (NG * NG);
  int i23 = combo % (NG * NG);
  float n2 = grid20(i23 / NG), n3 = grid20(i23 % NG);

  float r[NG];
#pragma unroll
  for (int i1 = 0; i1 < NG; i1++) r[i1] = -1.0f / grid20(i1);

  const float4* tab = reinterpret_cast<const float4*>(fws + OFF_TAB) + m * L;
  const float* tt = fws + OFF_T;

  float sg[NG], sgg[NG], sgt[NG];
#pragma unroll
  for (int i1 = 0; i1 < NG; i1++) { sg[i1] = 0.0f; sgg[i1] = 0.0f; sgt[i1] = 0.0f; }

  int base = ch * 1024 + lane;
  for (int it = 0; it < 16; ++it) {
    int l = base + it * 64;
    float4 tb = tab[l];
    float tv = tt[l];
    float lsum = log2f(exp2f(n2 * tb.x) + exp2f(n3 * tb.y));
    float spv = tb.z;
#pragma unroll
    for (int i1 = 0; i1 < NG; i1++) {
      float g = exp2f(r[i1] * lsum) * spv;
      sg[i1] += g;
      sgg[i1] = fmaf(g, g, sgg[i1]);
      sgt[i1] = fmaf(g, tv, sgt[i1]);
    }
  }

#pragma unroll
  for (int i1 = 0; i1 < NG; i1++) {
    for (int o = 32; o > 0; o >>= 1) {
      sg[i1]  += __shfl_down(sg[i1],  o);
      sgg[i1] += __shfl_down(sgg[i1], o);
      sgt[i1] += __shfl_down(sgt[i1], o);
    }
  }
  if (lane == 0) {
    float* dst = part + (combo * 2 + ch) * 60;
#pragma unroll
    for (int i1 = 0; i1 < NG; i1++) {
      dst[i1 * 3 + 0] = sg[i1];
      dst[i1 * 3 + 1] = sgg[i1];
      dst[i1 * 3 + 2] = sgt[i1];
    }
  }
}

// ---------------- block argmin helper --------------------------------------
__device__ __forceinline__ void block_argmin_to0(double& best, int& bi,
                                                 double* sbv, int* sbi) {
  int lane = threadIdx.x & 63, w = threadIdx.x >> 6;
  for (int o = 32; o > 0; o >>= 1) {
    double ob = __shfl_down(best, o);
    int oi = __shfl_down(bi, o);
    if (ob < best || (ob == best && oi < bi)) { best = ob; bi = oi; }
  }
  if (lane == 0) { sbv[w] = best; sbi[w] = bi; }
  __syncthreads();
  if (threadIdx.x == 0) {
    for (int k = 1; k < 4; k++) {
      if (sbv[k] < best || (sbv[k] == best && sbi[k] < bi)) { best = sbv[k]; bi = sbi[k]; }
    }
  }
}

// ---------------- K3: coarse finalize + argmin stage 1 ---------------------
// thread t = reference flat index; combine chunks, f64 mse, block argmin
__global__ __launch_bounds__(256) void k_cfin(const float* __restrict__ part,
                                              const double* __restrict__ dws,
                                              double* __restrict__ pv,
                                              int* __restrict__ pi) {
  int t = blockIdx.x * 256 + threadIdx.x;
  double best = 1e300; int bi = 0x7fffffff;
  if (t < NM * NG * NG * NG) {
    int m = t / (NG * NG * NG);
    int i1 = (t / (NG * NG)) % NG;
    int i23 = t % (NG * NG);
    int combo = m * (NG * NG) + i23;
    const float* p0 = part + combo * 120 + i1 * 3;
    double sg  = (double)p0[0] + (double)p0[60];
    double sgg = (double)p0[1] + (double)p0[61];
    double sgt = (double)p0[2] + (double)p0[62];
    double sum_t = dws[0], sum_tt = dws[1];
    double mean = sg / (double)L;
    double S = sgg - sg * sg / (double)L; if (S < 0.0) S = 0.0;
    double d = sqrt(S / (double)(L - 1)) + 1e-6;
    best = (S / (d * d) - 2.0 * (sgt - mean * sum_t) / d + sum_tt) / (double)L;
    bi = t;
  }
  __shared__ double sbv[4];
  __shared__ int sbi[4];
  block_argmin_to0(best, bi, sbv, sbi);
  if (threadIdx.x == 0) { pv[blockIdx.x] = best; pi[blockIdx.x] = bi; }
}

// ---------------- K4: fine partial sums (with in-block coarse argmin) ------
// wave = (combo=(j2,j3), jh in {0,1}, ec in {0,1}); 15 j1 x 3 accums per lane
__global__ __launch_bounds__(256) void k_fine(const float* __restrict__ fws,
                                              const double* __restrict__ pvc,
                                              const int* __restrict__ pic,
                                              float* __restrict__ partf) {
  __shared__ double sbv[4];
  __shared__ int sbi[4];
  __shared__ int s_ci;
  {
    double best = 1e300; int bi = 0x7fffffff;
    for (int i = threadIdx.x; i < NBC; i += 256) {
      double v = pvc[i]; int ix = pic[i];
      if (v < best || (v == best && ix < bi)) { best = v; bi = ix; }
    }
    block_argmin_to0(best, bi, sbv, sbi);
    if (threadIdx.x == 0) s_ci = bi;
  }
  __syncthreads();
  int ci = s_ci;
  int m  = ci / (NG * NG * NG);
  int rr = ci % (NG * NG * NG);
  float cn1 = grid20(rr / (NG * NG));
  float cn2 = grid20((rr / NG) % NG);
  float cn3 = grid20(rr % NG);

  int gwid = (blockIdx.x * 256 + threadIdx.x) >> 6;   // [0, 3600)
  int lane = threadIdx.x & 63;
  int combo = gwid >> 2;
  int sub = gwid & 3;
  int jh = sub >> 1, ec = sub & 1;
  int j2 = combo / NF, j3 = combo % NF;
  float n2 = finev(cn2, j2), n3 = finev(cn3, j3);

  float r[15];
#pragma unroll
  for (int q = 0; q < 15; q++) r[q] = -1.0f / finev(cn1, jh * 15 + q);

  const float4* tab = reinterpret_cast<const float4*>(fws + OFF_TAB) + m * L;
  const float* tt = fws + OFF_T;

  float sg[15], sgg[15], sgt[15];
#pragma unroll
  for (int q = 0; q < 15; q++) { sg[q] = 0.0f; sgg[q] = 0.0f; sgt[q] = 0.0f; }

  int base = ec * 1024 + lane;
  for (int it = 0; it < 16; ++it) {
    int l = base + it * 64;
    float4 tb = tab[l];
    float tv = tt[l];
    float lsum = log2f(exp2f(n2 * tb.x) + exp2f(n3 * tb.y));
    float spv = tb.z;
#pragma unroll
    for (int q = 0; q < 15; q++) {
      float g = exp2f(r[q] * lsum) * spv;
      sg[q] += g;
      sgg[q] = fmaf(g, g, sgg[q]);
      sgt[q] = fmaf(g, tv, sgt[q]);
    }
  }

#pragma unroll
  for (int q = 0; q < 15; q++) {
    for (int o = 32; o > 0; o >>= 1) {
      sg[q]  += __shfl_down(sg[q],  o);
      sgg[q] += __shfl_down(sgg[q], o);
      sgt[q] += __shfl_down(sgt[q], o);
    }
  }
  if (lane == 0) {
    float* dst = partf + (size_t)((combo * 2 + jh) * 15) * 6 + ec * 3;
#pragma unroll
    for (int q = 0; q < 15; q++) {
      dst[q * 6 + 0] = sg[q];
      dst[q * 6 + 1] = sgg[q];
      dst[q * 6 + 2] = sgt[q];
    }
  }
}

// ---------------- K5: fine finalize + argmin stage 1 -----------------------
__global__ __launch_bounds__(256) void k_ffin(const float* __restrict__ partf,
                                              const double* __restrict__ dws,
                                              double* __restrict__ pv,
                                              int* __restrict__ pi) {
  int t = blockIdx.x * 256 + threadIdx.x;   // reference fine flat index
  double best = 1e300; int bi = 0x7fffffff;
  if (t < NF * NF * NF) {
    int j1 = t / (NF * NF);
    int combo = t % (NF * NF);
    int jh = j1 / 15, j1l = j1 % 15;
    const float* p0 = partf + (size_t)((combo * 2 + jh) * 15 + j1l) * 6;
    double sg  = (double)p0[0] + (double)p0[3];
    double sgg = (double)p0[1] + (double)p0[4];
    double sgt = (double)p0[2] + (double)p0[5];
    double sum_t = dws[0], sum_tt = dws[1];
    double mean = sg / (double)L;
    double S = sgg - sg * sg / (double)L; if (S < 0.0) S = 0.0;
    double d = sqrt(S / (double)(L - 1)) + 1e-6;
    best = (S / (d * d) - 2.0 * (sgt - mean * sum_t) / d + sum_tt) / (double)L;
    bi = t;
  }
  __shared__ double sbv[4];
  __shared__ int sbi[4];
  block_argmin_to0(best, bi, sbv, sbi);
  if (threadIdx.x == 0) { pv[blockIdx.x] = best; pi[blockIdx.x] = bi; }
}

// ---------------- K6: final argmins + emit ---------------------------------
__global__ __launch_bounds__(256) void k_out(const double* __restrict__ pvc,
                                             const int* __restrict__ pic,
                                             const double* __restrict__ pvf,
                                             const int* __restrict__ pif,
                                             float* __restrict__ out) {
  __shared__ double sbv[4];
  __shared__ int sbi[4];
  __shared__ int s_ci;

  {
    double best = 1e300; int bi = 0x7fffffff;
    for (int i = threadIdx.x; i < NBC; i += 256) {
      double v = pvc[i]; int ix = pic[i];
      if (v < best || (v == best && ix < bi)) { best = v; bi = ix; }
    }
    block_argmin_to0(best, bi, sbv, sbi);
    if (threadIdx.x == 0) s_ci = bi;
  }
  __syncthreads();
  {
    double best = 1e300; int bi = 0x7fffffff;
    for (int i = threadIdx.x; i < NBF; i += 256) {
      double v = pvf[i]; int ix = pif[i];
      if (v < best || (v == best && ix < bi)) { best = v; bi = ix; }
    }
    block_argmin_to0(best, bi, sbv, sbi);
    if (threadIdx.x == 0) {
      int ci = s_ci;
      int m  = ci / (NG * NG * NG);
      int rr = ci % (NG * NG * NG);
      float cn1 = grid20(rr / (NG * NG));
      float cn2 = grid20((rr / NG) % NG);
      float cn3 = grid20(rr % NG);
      int fi = bi;
      int f1 = fi / (NF * NF), f2 = (fi / NF) % NF, f3 = fi % NF;
      out[0] = (float)(m + 1);
      out[1] = finev(cn1, f1);
      out[2] = finev(cn2, f2);
      out[3] = finev(cn3, f3);
    }
  }
}

extern "C" void kernel_launch(void* const* d_in, const int* in_sizes, int n_in,
                              void* d_out, int out_size, void* d_ws, size_t ws_size,
                              hipStream_t stream) {
  const float* x = (const float*)d_in[0];
  const int* freqp = (const int*)d_in[1];
  float* out = (float*)d_out;

  float* fws = (float*)d_ws;
  double* dws = (double*)(fws + FWS_FLOATS);        // 2 doubles (offset 335872, 8-aligned)
  float* part_c = (float*)(dws + 2);                // 4000 * 120 = 480000 floats
  float* part_f = part_c + 480000;                  // 900 * 180  = 162000 floats
  double* pvc = (double*)(part_f + 162000);         // NBC doubles (offset 8-aligned)
  double* pvf = pvc + NBC;                          // NBF doubles
  int* pic = (int*)(pvf + NBF);                     // NBC ints
  int* pif = pic + NBC;                             // NBF ints

  hipLaunchKernelGGL(k_init,   dim3(1 + (NM * L + 255) / 256), dim3(256), 0, stream,
                     x, freqp, fws, dws);
  hipLaunchKernelGGL(k_coarse, dim3(2000), dim3(256), 0, stream, fws, part_c);
  hipLaunchKernelGGL(k_cfin,   dim3(NBC),  dim3(256), 0, stream, part_c, dws, pvc, pic);
  hipLaunchKernelGGL(k_fine,   dim3(900),  dim3(256), 0, stream, fws, pvc, pic, part_f);
  hipLaunchKernelGGL(k_ffin,   dim3(NBF),  dim3(256), 0, stream, part_f, dws, pvf, pif);
  hipLaunchKernelGGL(k_out,    dim3(1),    dim3(256), 0, stream, pvc, pic, pvf, pif, out);
}